// Round 1
// baseline (87.848 us; speedup 1.0000x reference)
//
#include <hip/hip_runtime.h>
#include <math.h>

#define BB 32
#define CC 256
#define HH 64
#define WW 64
#define HWSZ 4096              // HH*WW
#define CHW 1048576            // CC*HWSZ

// ---------------------------------------------------------------------------
// Kernel A: channel-wise max + mean over C=256 for each (b, spatial).
// One thread per float2 of spatial positions; channel stride is HW floats,
// so consecutive lanes read consecutive addresses (coalesced, 512B/wave/instr).
// ---------------------------------------------------------------------------
__global__ void sg_reduce(const float* __restrict__ x,
                          float* __restrict__ maxp,
                          float* __restrict__ meanp) {
    int t = blockIdx.x * blockDim.x + threadIdx.x;   // < BB*HWSZ/2 = 65536
    int b  = t >> 11;                                // HWSZ/2 = 2048
    int s2 = t & 2047;
    const float2* xp = reinterpret_cast<const float2*>(x + (size_t)b * CHW) + s2;
    float2 v = xp[0];
    float2 mx = v;
    float2 sm = v;
    #pragma unroll 8
    for (int c = 1; c < CC; ++c) {
        float2 u = xp[(size_t)c * (HWSZ / 2)];
        mx.x = fmaxf(mx.x, u.x); mx.y = fmaxf(mx.y, u.y);
        sm.x += u.x;             sm.y += u.y;
    }
    reinterpret_cast<float2*>(maxp)[t] = mx;
    float2 mn;
    mn.x = sm.x * (1.0f / CC);
    mn.y = sm.y * (1.0f / CC);
    reinterpret_cast<float2*>(meanp)[t] = mn;
}

// ---------------------------------------------------------------------------
// Kernel B: 7x7 conv (2 in-ch -> 1 out-ch, same padding) + sigmoid.
// One thread per (b,h,w). Inputs (1 MB) are L2-resident; weights in LDS.
// ---------------------------------------------------------------------------
__global__ void sg_conv(const float* __restrict__ maxp,
                        const float* __restrict__ meanp,
                        const float* __restrict__ Wt,
                        float* __restrict__ scale) {
    __shared__ float w[98];
    int lt = threadIdx.x;
    if (lt < 98) w[lt] = Wt[lt];
    __syncthreads();

    int t = blockIdx.x * blockDim.x + lt;            // < BB*HWSZ = 131072
    int b = t >> 12;
    int s = t & 4095;
    int h = s >> 6;
    int wc = s & 63;
    const float* mb = maxp  + b * HWSZ;
    const float* nb = meanp + b * HWSZ;

    float acc = 0.0f;
    #pragma unroll
    for (int kh = 0; kh < 7; ++kh) {
        int hh = h + kh - 3;
        if ((unsigned)hh >= (unsigned)HH) continue;
        #pragma unroll
        for (int kw = 0; kw < 7; ++kw) {
            int wcol = wc + kw - 3;
            if ((unsigned)wcol >= (unsigned)WW) continue;
            int o = (hh << 6) + wcol;
            acc = fmaf(mb[o], w[kh * 7 + kw],      acc);
            acc = fmaf(nb[o], w[49 + kh * 7 + kw], acc);
        }
    }
    scale[t] = 1.0f / (1.0f + __expf(-acc));
}

// ---------------------------------------------------------------------------
// Kernel C: out = x * broadcast(scale).  float4 grid-stride elementwise.
// ---------------------------------------------------------------------------
__global__ void sg_apply(const float* __restrict__ x,
                         const float* __restrict__ scale,
                         float* __restrict__ out) {
    const int total4 = BB * CHW / 4;                 // 8388608
    int stride = gridDim.x * blockDim.x;
    for (int i = blockIdx.x * blockDim.x + threadIdx.x; i < total4; i += stride) {
        float4 v = reinterpret_cast<const float4*>(x)[i];
        int b  = i >> 18;                            // CHW/4 = 262144
        int s4 = i & 1023;                           // HWSZ/4 - 1
        float4 sc = reinterpret_cast<const float4*>(scale)[(b << 10) + s4];
        v.x *= sc.x; v.y *= sc.y; v.z *= sc.z; v.w *= sc.w;
        reinterpret_cast<float4*>(out)[i] = v;
    }
}

extern "C" void kernel_launch(void* const* d_in, const int* in_sizes, int n_in,
                              void* d_out, int out_size, void* d_ws, size_t ws_size,
                              hipStream_t stream) {
    const float* x  = (const float*)d_in[0];   // [32,256,64,64]
    const float* Wt = (const float*)d_in[1];   // [1,2,7,7] = 98 floats
    float* out = (float*)d_out;

    float* wsf   = (float*)d_ws;
    float* maxp  = wsf;                        // 131072 floats
    float* meanp = wsf + BB * HWSZ;            // 131072 floats
    float* scale = wsf + 2 * BB * HWSZ;        // 131072 floats

    // A: reduce over channels
    sg_reduce<<<(BB * HWSZ / 2) / 256, 256, 0, stream>>>(x, maxp, meanp);
    // B: conv + sigmoid
    sg_conv<<<(BB * HWSZ) / 256, 256, 0, stream>>>(maxp, meanp, Wt, scale);
    // C: apply gate
    sg_apply<<<2048, 256, 0, stream>>>(x, scale, out);
}

// Round 2
// 75.187 us; speedup vs baseline: 1.1684x; 1.1684x over previous
//
#include <hip/hip_runtime.h>
#include <math.h>

#define BB 32
#define CC 256
#define HH 64
#define WW 64
#define HWSZ 4096              // HH*WW
#define CHW 1048576            // CC*HWSZ

// ---------------------------------------------------------------------------
// Kernel A: channel-wise max + mean over C=256 for each (b, spatial).
// One block per (b, h) row: 2048 blocks -> 8 blocks/CU -> full occupancy.
// 256 threads = 16 channel-groups x 16 float4 spatial lanes; each thread
// reduces 16 channels (fully unrolled float4 loads), then LDS combine.
// ---------------------------------------------------------------------------
__global__ void sg_reduce(const float* __restrict__ x,
                          float* __restrict__ maxp,
                          float* __restrict__ meanp) {
    int bh = blockIdx.x;                 // b*64 + h
    int b  = bh >> 6;
    int h  = bh & 63;
    int w4 = threadIdx.x & 15;           // 16 float4 per 64-wide row
    int cg = threadIdx.x >> 4;           // 16 channel groups of 16

    const float4* base =
        reinterpret_cast<const float4*>(x + (size_t)b * CHW + h * WW) + w4;
    // channel stride in float4 units: HWSZ/4 = 1024
    float4 v = base[(size_t)(cg * 16) * 1024];
    float4 mx = v, sm = v;
    #pragma unroll
    for (int cc = 1; cc < 16; ++cc) {
        float4 u = base[(size_t)(cg * 16 + cc) * 1024];
        mx.x = fmaxf(mx.x, u.x); mx.y = fmaxf(mx.y, u.y);
        mx.z = fmaxf(mx.z, u.z); mx.w = fmaxf(mx.w, u.w);
        sm.x += u.x; sm.y += u.y; sm.z += u.z; sm.w += u.w;
    }

    __shared__ float4 lmax[16][16];
    __shared__ float4 lsum[16][16];
    lmax[cg][w4] = mx;
    lsum[cg][w4] = sm;
    __syncthreads();

    if (threadIdx.x < 16) {
        int w = threadIdx.x;
        float4 M = lmax[0][w];
        float4 S = lsum[0][w];
        #pragma unroll
        for (int g = 1; g < 16; ++g) {
            float4 m2 = lmax[g][w];
            float4 s2 = lsum[g][w];
            M.x = fmaxf(M.x, m2.x); M.y = fmaxf(M.y, m2.y);
            M.z = fmaxf(M.z, m2.z); M.w = fmaxf(M.w, m2.w);
            S.x += s2.x; S.y += s2.y; S.z += s2.z; S.w += s2.w;
        }
        reinterpret_cast<float4*>(maxp)[bh * 16 + w] = M;
        float4 mn;
        mn.x = S.x * (1.0f / CC); mn.y = S.y * (1.0f / CC);
        mn.z = S.z * (1.0f / CC); mn.w = S.w * (1.0f / CC);
        reinterpret_cast<float4*>(meanp)[bh * 16 + w] = mn;
    }
}

// ---------------------------------------------------------------------------
// Kernel B: 7x7 conv (2 in-ch -> 1 out-ch, same padding) + sigmoid.
// One thread per (b,h,w). Inputs (1 MB) are L2-resident; weights in LDS.
// ---------------------------------------------------------------------------
__global__ void sg_conv(const float* __restrict__ maxp,
                        const float* __restrict__ meanp,
                        const float* __restrict__ Wt,
                        float* __restrict__ scale) {
    __shared__ float w[98];
    int lt = threadIdx.x;
    if (lt < 98) w[lt] = Wt[lt];
    __syncthreads();

    int t = blockIdx.x * blockDim.x + lt;            // < BB*HWSZ = 131072
    int b = t >> 12;
    int s = t & 4095;
    int h = s >> 6;
    int wc = s & 63;
    const float* mb = maxp  + b * HWSZ;
    const float* nb = meanp + b * HWSZ;

    float acc = 0.0f;
    #pragma unroll
    for (int kh = 0; kh < 7; ++kh) {
        int hh = h + kh - 3;
        if ((unsigned)hh >= (unsigned)HH) continue;
        #pragma unroll
        for (int kw = 0; kw < 7; ++kw) {
            int wcol = wc + kw - 3;
            if ((unsigned)wcol >= (unsigned)WW) continue;
            int o = (hh << 6) + wcol;
            acc = fmaf(mb[o], w[kh * 7 + kw],      acc);
            acc = fmaf(nb[o], w[49 + kh * 7 + kw], acc);
        }
    }
    scale[t] = 1.0f / (1.0f + __expf(-acc));
}

// ---------------------------------------------------------------------------
// Kernel C: out = x * broadcast(scale).  float4 grid-stride elementwise.
// ---------------------------------------------------------------------------
__global__ void sg_apply(const float* __restrict__ x,
                         const float* __restrict__ scale,
                         float* __restrict__ out) {
    const int total4 = BB * CHW / 4;                 // 8388608
    int stride = gridDim.x * blockDim.x;
    for (int i = blockIdx.x * blockDim.x + threadIdx.x; i < total4; i += stride) {
        float4 v = reinterpret_cast<const float4*>(x)[i];
        int b  = i >> 18;                            // CHW/4 = 262144
        int s4 = i & 1023;                           // HWSZ/4 - 1
        float4 sc = reinterpret_cast<const float4*>(scale)[(b << 10) + s4];
        v.x *= sc.x; v.y *= sc.y; v.z *= sc.z; v.w *= sc.w;
        reinterpret_cast<float4*>(out)[i] = v;
    }
}

extern "C" void kernel_launch(void* const* d_in, const int* in_sizes, int n_in,
                              void* d_out, int out_size, void* d_ws, size_t ws_size,
                              hipStream_t stream) {
    const float* x  = (const float*)d_in[0];   // [32,256,64,64]
    const float* Wt = (const float*)d_in[1];   // [1,2,7,7] = 98 floats
    float* out = (float*)d_out;

    float* wsf   = (float*)d_ws;
    float* maxp  = wsf;                        // 131072 floats
    float* meanp = wsf + BB * HWSZ;            // 131072 floats
    float* scale = wsf + 2 * BB * HWSZ;        // 131072 floats

    // A: reduce over channels (one block per (b,h) row)
    sg_reduce<<<BB * HH, 256, 0, stream>>>(x, maxp, meanp);
    // B: conv + sigmoid
    sg_conv<<<(BB * HWSZ) / 256, 256, 0, stream>>>(maxp, meanp, Wt, scale);
    // C: apply gate
    sg_apply<<<2048, 256, 0, stream>>>(x, scale, out);
}

// Round 4
// 73.098 us; speedup vs baseline: 1.2018x; 1.0286x over previous
//
#include <hip/hip_runtime.h>
#include <math.h>

#define BB 32
#define CC 256
#define HH 64
#define WW 64
#define HWSZ 4096              // HH*WW
#define CHW 1048576            // CC*HWSZ

typedef float f4 __attribute__((ext_vector_type(4)));   // native vec4 for nt-store

// ---------------------------------------------------------------------------
// Kernel A: channel-wise max + mean over C=256 for each (b, spatial).
// One block per (b, h) row: 2048 blocks -> 8 blocks/CU -> full occupancy.
// 256 threads = 16 channel-groups x 16 float4 spatial lanes; each thread
// reduces 16 channels (fully unrolled float4 loads), then LDS combine.
// Regular (temporal) loads on purpose: we WANT x resident in L3 for kernel B.
// ---------------------------------------------------------------------------
__global__ void sg_reduce(const float* __restrict__ x,
                          float* __restrict__ maxp,
                          float* __restrict__ meanp) {
    int bh = blockIdx.x;                 // b*64 + h
    int b  = bh >> 6;
    int h  = bh & 63;
    int w4 = threadIdx.x & 15;           // 16 float4 per 64-wide row
    int cg = threadIdx.x >> 4;           // 16 channel groups of 16

    const f4* base =
        reinterpret_cast<const f4*>(x + (size_t)b * CHW + h * WW) + w4;
    // channel stride in float4 units: HWSZ/4 = 1024
    f4 v = base[(size_t)(cg * 16) * 1024];
    f4 mx = v, sm = v;
    #pragma unroll
    for (int cc = 1; cc < 16; ++cc) {
        f4 u = base[(size_t)(cg * 16 + cc) * 1024];
        mx.x = fmaxf(mx.x, u.x); mx.y = fmaxf(mx.y, u.y);
        mx.z = fmaxf(mx.z, u.z); mx.w = fmaxf(mx.w, u.w);
        sm += u;
    }

    __shared__ f4 lmax[16][16];
    __shared__ f4 lsum[16][16];
    lmax[cg][w4] = mx;
    lsum[cg][w4] = sm;
    __syncthreads();

    if (threadIdx.x < 16) {
        int w = threadIdx.x;
        f4 M = lmax[0][w];
        f4 S = lsum[0][w];
        #pragma unroll
        for (int g = 1; g < 16; ++g) {
            f4 m2 = lmax[g][w];
            S += lsum[g][w];
            M.x = fmaxf(M.x, m2.x); M.y = fmaxf(M.y, m2.y);
            M.z = fmaxf(M.z, m2.z); M.w = fmaxf(M.w, m2.w);
        }
        reinterpret_cast<f4*>(maxp)[bh * 16 + w] = M;
        reinterpret_cast<f4*>(meanp)[bh * 16 + w] = S * (1.0f / CC);
    }
}

// ---------------------------------------------------------------------------
// Kernel B (fused): 7x7 conv + sigmoid for one (b,h) row -> LDS, then
// stream all 256 channels of that row: out = x * scale.
// Conv inputs (1 MB planes) are L2-resident. out written with non-temporal
// stores so the 134 MB of writes don't evict x from L3 (x was just read by
// kernel A; its re-read here should be L3-served).
// ---------------------------------------------------------------------------
__global__ void sg_conv_apply(const float* __restrict__ x,
                              const float* __restrict__ maxp,
                              const float* __restrict__ meanp,
                              const float* __restrict__ Wt,
                              float* __restrict__ out) {
    __shared__ float sscale[WW];
    int bh = blockIdx.x;                 // b*64 + h
    int b  = bh >> 6;
    int h  = bh & 63;
    int tid = threadIdx.x;

    if (tid < WW) {
        int wc = tid;
        const float* mb = maxp  + b * HWSZ;
        const float* nb = meanp + b * HWSZ;
        float acc = 0.0f;
        #pragma unroll
        for (int kh = 0; kh < 7; ++kh) {
            int hh = h + kh - 3;
            if ((unsigned)hh >= (unsigned)HH) continue;
            #pragma unroll
            for (int kw = 0; kw < 7; ++kw) {
                int wcol = wc + kw - 3;
                if ((unsigned)wcol >= (unsigned)WW) continue;
                int o = (hh << 6) + wcol;
                acc = fmaf(mb[o], Wt[kh * 7 + kw],      acc);
                acc = fmaf(nb[o], Wt[49 + kh * 7 + kw], acc);
            }
        }
        sscale[wc] = 1.0f / (1.0f + __expf(-acc));
    }
    __syncthreads();

    int w4 = tid & 15;                   // float4 lane within the row
    int cg = tid >> 4;                   // 16 channel groups of 16
    f4 sc = reinterpret_cast<const f4*>(sscale)[w4];

    const f4* xb =
        reinterpret_cast<const f4*>(x + (size_t)b * CHW + h * WW) + w4;
    f4* ob =
        reinterpret_cast<f4*>(out + (size_t)b * CHW + h * WW) + w4;

    #pragma unroll
    for (int cc = 0; cc < 16; ++cc) {
        size_t off = (size_t)(cg * 16 + cc) * 1024;   // channel stride (f4)
        f4 v = xb[off];
        v *= sc;
        __builtin_nontemporal_store(v, ob + off);
    }
}

extern "C" void kernel_launch(void* const* d_in, const int* in_sizes, int n_in,
                              void* d_out, int out_size, void* d_ws, size_t ws_size,
                              hipStream_t stream) {
    const float* x  = (const float*)d_in[0];   // [32,256,64,64]
    const float* Wt = (const float*)d_in[1];   // [1,2,7,7] = 98 floats
    float* out = (float*)d_out;

    float* wsf   = (float*)d_ws;
    float* maxp  = wsf;                        // 131072 floats
    float* meanp = wsf + BB * HWSZ;            // 131072 floats

    // A: reduce over channels (one block per (b,h) row)
    sg_reduce<<<BB * HH, 256, 0, stream>>>(x, maxp, meanp);
    // B: conv + sigmoid + apply (one block per (b,h) row)
    sg_conv_apply<<<BB * HH, 256, 0, stream>>>(x, maxp, meanp, Wt, out);
}